// Round 7
// baseline (698.976 us; speedup 1.0000x reference)
//
#include <hip/hip_runtime.h>
#include <math.h>
#include <stdint.h>

typedef float f4u __attribute__((ext_vector_type(4), aligned(4)));
typedef __attribute__((ext_vector_type(8))) short short8;   // 8 bf16 (4 VGPR)
typedef __attribute__((ext_vector_type(4))) float float4v;  // MFMA acc

#define DIM 256
#define KCB 1024
#define PERP_OFF 16777217
#define ENC_OFF  16777218
#define CAP 32
#define EPS 0.008f
#define NPB 64             // n per mega block (= one (b,h) row)
#define MEGA_BLOCKS 1024   // 1024 * 64 = 65536 n

// ---------------------------------------------------------------------------
// numpy pairwise sum-of-squares of a 128-block (8 accumulators, pairwise
// combine); squares rounded separately; no fma contraction.
// ---------------------------------------------------------------------------
__device__ __forceinline__ float np_sumsq128(const float* a, int stride) {
  float r[8];
  #pragma unroll
  for (int j = 0; j < 8; ++j) { float v = a[j * stride]; r[j] = __fmul_rn(v, v); }
  #pragma unroll
  for (int i = 8; i < 128; i += 8) {
    #pragma unroll
    for (int j = 0; j < 8; ++j) {
      float v = a[(i + j) * stride];
      r[j] = __fadd_rn(r[j], __fmul_rn(v, v));
    }
  }
  float s01 = __fadd_rn(r[0], r[1]);
  float s23 = __fadd_rn(r[2], r[3]);
  float s45 = __fadd_rn(r[4], r[5]);
  float s67 = __fadd_rn(r[6], r[7]);
  return __fadd_rn(__fadd_rn(s01, s23), __fadd_rn(s45, s67));
}

__device__ __forceinline__ unsigned short f2bf(float f) {
  unsigned u = __float_as_uint(f);
  u += 0x7FFFu + ((u >> 16) & 1u);     // RNE
  return (unsigned short)(u >> 16);
}

// ---------------------------------------------------------------------------
// k_prep: e_bf16[k][d], np-exact cb_sq[k], zero counts. grid 1024 x 64.
// ---------------------------------------------------------------------------
__global__ __launch_bounds__(64)
void k_prep(const float* __restrict__ cb, unsigned short* __restrict__ e_bf16,
            float* __restrict__ cb_sq, int* __restrict__ counts) {
  const int k = blockIdx.x;
  const int l = threadIdx.x;                  // 0..63
  float4 v = ((const float4*)(cb + k * DIM))[l];
  unsigned short bs[4] = {f2bf(v.x), f2bf(v.y), f2bf(v.z), f2bf(v.w)};
  *(ushort4*)(e_bf16 + k * DIM + l * 4) = *(ushort4*)bs;
  if (l == 0) {
    const float* p = cb + k * DIM;
    cb_sq[k] = __fadd_rn(np_sumsq128(p, 1), np_sumsq128(p + 128, 1));
    counts[k] = 0;
  }
}

// ---------------------------------------------------------------------------
// k_mega v2: score + filter + insq + refine + epilogue, ONE block per 64-n
// tile = one (b,h) row. 1024 blocks x 256 thr, ~13KB LDS, Bf[8] (1 n-group
// per wave) -> 4-6 blocks/CU (R6 was 2: Occ 20%, all pipes <25%).
//  P0 score: bf16 MFMA approx s = cb_sq[k]-2*dot, online capture vs running
//     cross-lane min (superset; exact set recovered by the end filter).
//     Per-n chains identical to R6.
//  P1 filter (t<64, in LDS) || insq (t in [64,192), 2 threads/n computing
//     the two np_sumsq128 halves; __fadd_rn at refine -> bit-identical).
//  P2 refine: 4 threads/n (R5-verified); per-candidate fmaf chains bitwise
//     unchanged; lexmin over (dist,idx) is partition-free; 2x shfl_xor.
//     Overflow (cnt>CAP) -> exact full scan.
//  P3/P4 epilogue: verbatim (enc one-hot nontemporal, xq + double loss).
// ---------------------------------------------------------------------------
__global__ __launch_bounds__(256, 6)
void k_mega(const float* __restrict__ x, const float* __restrict__ cb,
            const unsigned short* __restrict__ e_bf16,
            const float* __restrict__ cb_sq,
            float* __restrict__ out1, float* __restrict__ enc,
            int* __restrict__ counts, double* __restrict__ partials) {
  __shared__ unsigned int   lcnt[NPB];
  __shared__ unsigned short llist[NPB * CAP];   // 4KB
  __shared__ float          lsc[NPB * CAP];     // 8KB
  __shared__ float          lmin[NPB];
  __shared__ float          hpart[2 * NPB];     // insq halves
  __shared__ int            idxs[NPB];
  __shared__ double         sm[4];

  const int t    = threadIdx.x;
  const int wv   = t >> 6;
  const int lane = t & 63;
  const int l15  = lane & 15;
  const int quad = lane >> 4;
  const int blk  = blockIdx.x;                  // == bh
  if (t < NPB) lcnt[t] = 0;
  __syncthreads();

  // ---- P0a: B-frag setup: one 16-n group per wave, 8 K-steps ----
  short8 Bf[8];
  {
    const int n = blk * NPB + wv * 16 + l15;
    const float* xb = x + (n >> 12) * 1048576 + (n & 4095);
    #pragma unroll
    for (int ks = 0; ks < 8; ++ks) {
      const int d0 = ks * 32 + quad * 8;
      union { unsigned short s[8]; short8 v; } u;
      #pragma unroll
      for (int j = 0; j < 8; ++j) u.s[j] = f2bf(xb[(d0 + j) * 4096]);
      Bf[ks] = u.v;
    }
  }

  // ---- P0b: single pass MFMA + online min + online capture ----
  float m = 1e30f;
  for (int ct = 0; ct < 64; ++ct) {
    float4v acc = (float4v){0.f, 0.f, 0.f, 0.f};
    const unsigned short* ap = e_bf16 + (ct * 16 + l15) * DIM + quad * 8;
    #pragma unroll
    for (int ks = 0; ks < 8; ++ks) {
      const short8 a = *(const short8*)(ap + ks * 32);
      acc = __builtin_amdgcn_mfma_f32_16x16x32_bf16(a, Bf[ks], acc, 0, 0, 0);
    }
    const float4 cs = *(const float4*)(cb_sq + ct * 16 + quad * 4);
    const float sa[4] = {fmaf(-2.f, acc.x, cs.x), fmaf(-2.f, acc.y, cs.y),
                         fmaf(-2.f, acc.z, cs.z), fmaf(-2.f, acc.w, cs.w)};
    // running cross-lane min for this n (fmin exact -> order-independent)
    float bm = fminf(fminf(sa[0], sa[1]), fminf(sa[2], sa[3]));
    const float sblk = bm;
    bm = fminf(bm, m);
    bm = fminf(bm, __shfl_xor(bm, 16));
    bm = fminf(bm, __shfl_xor(bm, 32));
    m = bm;
    const float thr = bm + EPS;
    if (sblk <= thr) {                 // rare: skip whole capture block
      const int nl = wv * 16 + l15;
      #pragma unroll
      for (int r = 0; r < 4; ++r) {
        if (sa[r] <= thr) {
          unsigned slot = atomicAdd(&lcnt[nl], 1u);
          if (slot < CAP) {
            llist[nl * CAP + slot] = (unsigned short)(ct * 16 + quad * 4 + r);
            lsc[nl * CAP + slot]   = sa[r];
          }
        }
      }
    }
  }
  if (quad == 0) lmin[wv * 16 + l15] = m;
  __syncthreads();

  // ---- P1: filter (t<64) || insq halves (t in [64,192)) ----
  if (t < NPB) {
    const unsigned cnt = lcnt[t];
    unsigned outc = cnt;
    if (cnt <= CAP) {
      const float thrf = lmin[t] + EPS;
      unsigned j = 0;
      for (unsigned i = 0; i < cnt; ++i) {
        const unsigned short c = llist[t * CAP + i];
        if (lsc[t * CAP + i] <= thrf) llist[t * CAP + j++] = c;
      }
      outc = j;
    }
    lcnt[t] = outc;
  } else if (t < 64 + 2 * NPB) {
    const int tt = t - 64;            // 0..127
    const int nl = tt >> 1;
    const int p  = tt & 1;
    const int n  = blk * NPB + nl;
    const float* xp = x + (n >> 12) * 1048576 + (n & 4095) + p * 128 * 4096;
    hpart[tt] = np_sumsq128(xp, 4096);
  }
  __syncthreads();

  // ---- P2: refine, 4 threads per n ----
  {
    const int nl = t >> 2;            // 0..63
    const int q  = t & 3;
    const int n  = blk * NPB + nl;
    const unsigned cnt = lcnt[nl];
    const float* xb = x + (n >> 12) * 1048576 + (n & 4095);
    const float isq = __fadd_rn(hpart[2 * nl], hpart[2 * nl + 1]);
    float bv = 1e30f; int bc = 0x7FFFFFFF;

    if (cnt <= CAP) {
      const unsigned short* lst = llist + nl * CAP;
      for (unsigned i = q; i < cnt; i += 4) {
        const int c1 = lst[i];
        const float4* e1 = (const float4*)(cb + c1 * DIM);
        float d1 = 0.f;
        #pragma unroll 4
        for (int qq = 0; qq < 64; ++qq) {
          const float4 a = e1[qq];
          d1 = fmaf(xb[(qq * 4 + 0) * 4096], a.x, d1);
          d1 = fmaf(xb[(qq * 4 + 1) * 4096], a.y, d1);
          d1 = fmaf(xb[(qq * 4 + 2) * 4096], a.z, d1);
          d1 = fmaf(xb[(qq * 4 + 3) * 4096], a.w, d1);
        }
        const float dist = __fsub_rn(__fadd_rn(isq, cb_sq[c1]), __fmul_rn(2.f, d1));
        if (dist < bv || (dist == bv && c1 < bc)) { bv = dist; bc = c1; }
      }
    } else {
      // overflow fallback (P ~ 1e-9): exact full scan
      for (int c = q; c < KCB; c += 4) {
        const float4* e1 = (const float4*)(cb + c * DIM);
        float d1 = 0.f;
        #pragma unroll 4
        for (int qq = 0; qq < 64; ++qq) {
          const float4 a = e1[qq];
          d1 = fmaf(xb[(qq * 4 + 0) * 4096], a.x, d1);
          d1 = fmaf(xb[(qq * 4 + 1) * 4096], a.y, d1);
          d1 = fmaf(xb[(qq * 4 + 2) * 4096], a.z, d1);
          d1 = fmaf(xb[(qq * 4 + 3) * 4096], a.w, d1);
        }
        const float dist = __fsub_rn(__fadd_rn(isq, cb_sq[c]), __fmul_rn(2.f, d1));
        if (dist < bv || (dist == bv && c < bc)) { bv = dist; bc = c; }
      }
    }
    // combine 4 lanes (lexmin -> order independent)
    {
      float ov = __shfl_xor(bv, 1); int oc = __shfl_xor(bc, 1);
      if (ov < bv || (ov == bv && oc < bc)) { bv = ov; bc = oc; }
      ov = __shfl_xor(bv, 2); oc = __shfl_xor(bc, 2);
      if (ov < bv || (ov == bv && oc < bc)) { bv = ov; bc = oc; }
    }
    if (q == 0) { idxs[nl] = bc; atomicAdd(counts + bc, 1); }
  }
  __syncthreads();

  // ---- P3: one-hot encodings (coalesced, nontemporal) ----
  const int bh = blk;
  const int b  = bh >> 6, h = bh & 63;
  {
    float* base = enc + (size_t)bh * 65536 + t * 4;
    #pragma unroll 8
    for (int r = 0; r < 64; ++r) {
      const int bi = idxs[r];
      f4u v = {0.f, 0.f, 0.f, 0.f};
      if ((bi >> 2) == t) {
        if ((bi & 3) == 0) v.x = 1.f; else if ((bi & 3) == 1) v.y = 1.f;
        else if ((bi & 3) == 2) v.z = 1.f; else v.w = 1.f;
      }
      __builtin_nontemporal_store(v, (f4u*)(base + r * 1024));
    }
  }

  // ---- P4: xq straight-through + double loss partial ----
  const int w4 = (t & 15) * 4;
  const int cg = t >> 4;
  float qf[4][16];
  #pragma unroll
  for (int i = 0; i < 4; ++i) {
    const float4* rp = (const float4*)(cb + idxs[w4 + i] * DIM + cg * 16);
    #pragma unroll
    for (int jq = 0; jq < 4; ++jq) {
      const float4 v = rp[jq];
      qf[i][jq * 4 + 0] = v.x; qf[i][jq * 4 + 1] = v.y;
      qf[i][jq * 4 + 2] = v.z; qf[i][jq * 4 + 3] = v.w;
    }
  }

  double s = 0.0;
  #pragma unroll
  for (int j = 0; j < 16; ++j) {
    const int c = cg * 16 + j;
    const size_t off = ((size_t)b << 20) + ((size_t)c << 12) + (h << 6) + w4;
    const float4 xp = *(const float4*)(x + off);
    const float q0 = qf[0][j], q1 = qf[1][j], q2 = qf[2][j], q3 = qf[3][j];
    const float d0 = __fsub_rn(q0, xp.x), d1 = __fsub_rn(q1, xp.y);
    const float d2 = __fsub_rn(q2, xp.z), d3 = __fsub_rn(q3, xp.w);
    f4u o;
    o.x = __fadd_rn(xp.x, d0); o.y = __fadd_rn(xp.y, d1);
    o.z = __fadd_rn(xp.z, d2); o.w = __fadd_rn(xp.w, d3);
    __builtin_nontemporal_store(o, (f4u*)(out1 + off));
    s += (double)(d0*d0) + (double)(d1*d1) + (double)(d2*d2) + (double)(d3*d3);
  }
  #pragma unroll
  for (int off = 32; off > 0; off >>= 1) s += __shfl_down(s, off);
  if ((t & 63) == 0) sm[t >> 6] = s;
  __syncthreads();
  if (t == 0) partials[bh] = (sm[0] + sm[1]) + (sm[2] + sm[3]);
}

// ---------------------------------------------------------------------------
// k_final: loss + perplexity. grid 1 x 256
// ---------------------------------------------------------------------------
__global__ __launch_bounds__(256)
void k_final(const double* __restrict__ partials, const int* __restrict__ counts,
             float* __restrict__ out) {
  const int t = threadIdx.x;
  double s = 0.0;
  #pragma unroll
  for (int i = 0; i < 4; ++i) s += partials[t + i * 256];
  #pragma unroll
  for (int off = 32; off > 0; off >>= 1) s += __shfl_down(s, off);
  __shared__ double sm[4];
  __shared__ float smf[4];
  if ((t & 63) == 0) sm[t >> 6] = s;

  float ps = 0.f;
  #pragma unroll
  for (int i = 0; i < 4; ++i) {
    const float p = (float)counts[t + i * 256] * (1.0f / 65536.0f);
    ps += p * logf(1.0e10f + p);
  }
  #pragma unroll
  for (int off = 32; off > 0; off >>= 1) ps += __shfl_down(ps, off);
  if ((t & 63) == 0) smf[t >> 6] = ps;
  __syncthreads();
  if (t == 0) {
    const double tot = (sm[0] + sm[1]) + (sm[2] + sm[3]);
    const float mval = (float)(tot / 16777216.0);
    out[0] = mval + 0.25f * mval;
    out[PERP_OFF] = expf(-((smf[0] + smf[1]) + (smf[2] + smf[3])));
  }
}

// ---------------------------------------------------------------------------
extern "C" void kernel_launch(void* const* d_in, const int* in_sizes, int n_in,
                              void* d_out, int out_size, void* d_ws, size_t ws_size,
                              hipStream_t stream) {
  const float* x  = (const float*)d_in[0];   // (16,256,64,64) fp32
  const float* cb = (const float*)d_in[1];   // (1024,256) fp32
  float* out = (float*)d_out;
  char*  ws  = (char*)d_ws;

  int*            counts   = (int*)(ws + 0);                //   4 KB
  float*          cb_sq    = (float*)(ws + 4096);           //   4 KB
  double*         partials = (double*)(ws + 8192);          //   8 KB
  unsigned short* e_bf16   = (unsigned short*)(ws + 16384); // 512 KB

  k_prep <<<1024, 64, 0, stream>>>(cb, e_bf16, cb_sq, counts);
  k_mega <<<MEGA_BLOCKS, 256, 0, stream>>>(x, cb, e_bf16, cb_sq, out + 1,
                                           out + ENC_OFF, counts, partials);
  k_final<<<1, 256, 0, stream>>>(partials, counts, out);
}

// Round 8
// 640.861 us; speedup vs baseline: 1.0907x; 1.0907x over previous
//
#include <hip/hip_runtime.h>
#include <math.h>
#include <stdint.h>

typedef float f4u __attribute__((ext_vector_type(4), aligned(4)));
typedef __attribute__((ext_vector_type(8))) short short8;   // 8 bf16 (4 VGPR)
typedef __attribute__((ext_vector_type(4))) float float4v;  // MFMA acc

#define DIM 256
#define KCB 1024
#define PERP_OFF 16777217
#define ENC_OFF  16777218
#define CAP 32
#define EPS 0.008f
#define NPB 64             // n per mega block (= one (b,h) row)
#define MEGA_BLOCKS 1024   // 1024 * 64 = 65536 n

// ---------------------------------------------------------------------------
// numpy pairwise sum-of-squares of a 128-block (8 accumulators, pairwise
// combine); squares rounded separately; no fma contraction.
// ---------------------------------------------------------------------------
__device__ __forceinline__ float np_sumsq128(const float* a, int stride) {
  float r[8];
  #pragma unroll
  for (int j = 0; j < 8; ++j) { float v = a[j * stride]; r[j] = __fmul_rn(v, v); }
  #pragma unroll
  for (int i = 8; i < 128; i += 8) {
    #pragma unroll
    for (int j = 0; j < 8; ++j) {
      float v = a[(i + j) * stride];
      r[j] = __fadd_rn(r[j], __fmul_rn(v, v));
    }
  }
  float s01 = __fadd_rn(r[0], r[1]);
  float s23 = __fadd_rn(r[2], r[3]);
  float s45 = __fadd_rn(r[4], r[5]);
  float s67 = __fadd_rn(r[6], r[7]);
  return __fadd_rn(__fadd_rn(s01, s23), __fadd_rn(s45, s67));
}

__device__ __forceinline__ unsigned short f2bf(float f) {
  unsigned u = __float_as_uint(f);
  u += 0x7FFFu + ((u >> 16) & 1u);     // RNE
  return (unsigned short)(u >> 16);
}

// ---------------------------------------------------------------------------
// k_prep: e_bf16[k][d], np-exact cb_sq[k], zero counts. grid 1024 x 64.
// ---------------------------------------------------------------------------
__global__ __launch_bounds__(64)
void k_prep(const float* __restrict__ cb, unsigned short* __restrict__ e_bf16,
            float* __restrict__ cb_sq, int* __restrict__ counts) {
  const int k = blockIdx.x;
  const int l = threadIdx.x;                  // 0..63
  float4 v = ((const float4*)(cb + k * DIM))[l];
  unsigned short bs[4] = {f2bf(v.x), f2bf(v.y), f2bf(v.z), f2bf(v.w)};
  *(ushort4*)(e_bf16 + k * DIM + l * 4) = *(ushort4*)bs;
  if (l == 0) {
    const float* p = cb + k * DIM;
    cb_sq[k] = __fadd_rn(np_sumsq128(p, 1), np_sumsq128(p + 128, 1));
    counts[k] = 0;
  }
}

// ---------------------------------------------------------------------------
// SCORE_STEP: one ct iteration of the score loop.
//  - prefetches ct+1's A-frags into NXT (reg double-buffer; CT+1 wraps &63
//    so the final prefetch stays in-bounds and is simply unused)
//  - 8-MFMA chain on CUR
//  - TIGHT=1: per-ct cross-quad reduce (R7-exact, used for cts 0..3 to
//    initialize thr); TIGHT=0: capture vs stale thr (>= running global min
//    >= m_final  -> captured set is a SUPERSET of the exact set; the end
//    filter vs m_final+EPS recovers the exact set -> bitwise-identical
//    downstream).
// mlane = per-lane cumulative min of own-quad codes (never reset).
// ---------------------------------------------------------------------------
#define SCORE_STEP(CT, CUR, NXT, TIGHT)                                        \
  {                                                                            \
    const int nct_ = ((CT) + 1) & 63;                                          \
    const unsigned short* np_ = e_bf16 + (nct_ * 16 + l15) * DIM + quad * 8;   \
    _Pragma("unroll")                                                          \
    for (int ks = 0; ks < 8; ++ks) NXT[ks] = *(const short8*)(np_ + ks * 32);  \
    float4v acc = (float4v){0.f, 0.f, 0.f, 0.f};                               \
    _Pragma("unroll")                                                          \
    for (int ks = 0; ks < 8; ++ks)                                             \
      acc = __builtin_amdgcn_mfma_f32_16x16x32_bf16(CUR[ks], Bf[ks], acc, 0, 0, 0); \
    const float4 cs = *(const float4*)(cb_sq + (CT) * 16 + quad * 4);          \
    float sa[4];                                                               \
    sa[0] = fmaf(-2.f, acc.x, cs.x); sa[1] = fmaf(-2.f, acc.y, cs.y);          \
    sa[2] = fmaf(-2.f, acc.z, cs.z); sa[3] = fmaf(-2.f, acc.w, cs.w);          \
    const float cmin_ = fminf(fminf(sa[0], sa[1]), fminf(sa[2], sa[3]));       \
    mlane = fminf(mlane, cmin_);                                               \
    if (TIGHT) {                                                               \
      float bm_ = fminf(mlane, __shfl_xor(mlane, 16));                         \
      bm_ = fminf(bm_, __shfl_xor(bm_, 32));                                   \
      mfin = bm_;                                                              \
      thr = bm_ + EPS;                                                         \
    }                                                                          \
    if (cmin_ <= thr) {                                                        \
      const int nl_ = wv * 16 + l15;                                           \
      _Pragma("unroll")                                                        \
      for (int r = 0; r < 4; ++r) {                                            \
        if (sa[r] <= thr) {                                                    \
          unsigned slot = atomicAdd(&lcnt[nl_], 1u);                           \
          if (slot < CAP) {                                                    \
            llist[nl_ * CAP + slot] = (unsigned short)((CT) * 16 + quad * 4 + r); \
            lsc[nl_ * CAP + slot]   = sa[r];                                   \
          }                                                                    \
        }                                                                      \
      }                                                                        \
    }                                                                          \
  }

// ---------------------------------------------------------------------------
// k_mega v3: score + filter + insq + refine + epilogue, one block per (b,h).
// v3: A-frag register double-buffer (load ct+1 under ct's MFMAs) + windowed
// stale-threshold capture (cross-quad shfl pair once per 4 cts, off the
// critical path) — attacks R7's two serial latency chains.
// ---------------------------------------------------------------------------
__global__ __launch_bounds__(256, 3)
void k_mega(const float* __restrict__ x, const float* __restrict__ cb,
            const unsigned short* __restrict__ e_bf16,
            const float* __restrict__ cb_sq,
            float* __restrict__ out1, float* __restrict__ enc,
            int* __restrict__ counts, double* __restrict__ partials) {
  __shared__ unsigned int   lcnt[NPB];
  __shared__ unsigned short llist[NPB * CAP];   // 4KB
  __shared__ float          lsc[NPB * CAP];     // 8KB
  __shared__ float          lmin[NPB];
  __shared__ float          hpart[2 * NPB];     // insq halves
  __shared__ int            idxs[NPB];
  __shared__ double         sm[4];

  const int t    = threadIdx.x;
  const int wv   = t >> 6;
  const int lane = t & 63;
  const int l15  = lane & 15;
  const int quad = lane >> 4;
  const int blk  = blockIdx.x;                  // == bh
  if (t < NPB) lcnt[t] = 0;
  __syncthreads();

  // ---- P0a: B-frag setup: one 16-n group per wave, 8 K-steps ----
  short8 Bf[8];
  {
    const int n = blk * NPB + wv * 16 + l15;
    const float* xb = x + (n >> 12) * 1048576 + (n & 4095);
    #pragma unroll
    for (int ks = 0; ks < 8; ++ks) {
      const int d0 = ks * 32 + quad * 8;
      union { unsigned short s[8]; short8 v; } u;
      #pragma unroll
      for (int j = 0; j < 8; ++j) u.s[j] = f2bf(xb[(d0 + j) * 4096]);
      Bf[ks] = u.v;
    }
  }

  // ---- P0b: score loop with A double-buffer + windowed capture ----
  float mlane = 1e30f, thr = 1e30f, mfin = 1e30f;
  short8 aA[8], aB[8];
  {
    const unsigned short* p0 = e_bf16 + l15 * DIM + quad * 8;   // ct = 0
    #pragma unroll
    for (int ks = 0; ks < 8; ++ks) aA[ks] = *(const short8*)(p0 + ks * 32);
  }
  // prologue: cts 0..3 tight (initializes thr; exact R7 per-ct semantics)
  SCORE_STEP(0, aA, aB, 1)
  SCORE_STEP(1, aB, aA, 1)
  SCORE_STEP(2, aA, aB, 1)
  SCORE_STEP(3, aB, aA, 1)
  // main: windows of 4 cts, stale thr; reduce once per window
  for (int ctw = 4; ctw < 64; ctw += 4) {
    SCORE_STEP(ctw + 0, aA, aB, 0)
    SCORE_STEP(ctw + 1, aB, aA, 0)
    SCORE_STEP(ctw + 2, aA, aB, 0)
    SCORE_STEP(ctw + 3, aB, aA, 0)
    float mr = fminf(mlane, __shfl_xor(mlane, 16));
    mr = fminf(mr, __shfl_xor(mr, 32));
    mfin = mr;
    thr = mr + EPS;
  }
  if (quad == 0) lmin[wv * 16 + l15] = mfin;
  __syncthreads();

  // ---- P1: filter (t<64) || insq halves (t in [64,192)) ----
  if (t < NPB) {
    const unsigned cnt = lcnt[t];
    unsigned outc = cnt;
    if (cnt <= CAP) {
      const float thrf = lmin[t] + EPS;
      unsigned j = 0;
      for (unsigned i = 0; i < cnt; ++i) {
        const unsigned short c = llist[t * CAP + i];
        if (lsc[t * CAP + i] <= thrf) llist[t * CAP + j++] = c;
      }
      outc = j;
    }
    lcnt[t] = outc;
  } else if (t < 64 + 2 * NPB) {
    const int tt = t - 64;            // 0..127
    const int nl = tt >> 1;
    const int p  = tt & 1;
    const int n  = blk * NPB + nl;
    const float* xp = x + (n >> 12) * 1048576 + (n & 4095) + p * 128 * 4096;
    hpart[tt] = np_sumsq128(xp, 4096);
  }
  __syncthreads();

  // ---- P2: refine, 4 threads per n ----
  {
    const int nl = t >> 2;            // 0..63
    const int q  = t & 3;
    const int n  = blk * NPB + nl;
    const unsigned cnt = lcnt[nl];
    const float* xb = x + (n >> 12) * 1048576 + (n & 4095);
    const float isq = __fadd_rn(hpart[2 * nl], hpart[2 * nl + 1]);
    float bv = 1e30f; int bc = 0x7FFFFFFF;

    if (cnt <= CAP) {
      const unsigned short* lst = llist + nl * CAP;
      for (unsigned i = q; i < cnt; i += 4) {
        const int c1 = lst[i];
        const float4* e1 = (const float4*)(cb + c1 * DIM);
        float d1 = 0.f;
        #pragma unroll 4
        for (int qq = 0; qq < 64; ++qq) {
          const float4 a = e1[qq];
          d1 = fmaf(xb[(qq * 4 + 0) * 4096], a.x, d1);
          d1 = fmaf(xb[(qq * 4 + 1) * 4096], a.y, d1);
          d1 = fmaf(xb[(qq * 4 + 2) * 4096], a.z, d1);
          d1 = fmaf(xb[(qq * 4 + 3) * 4096], a.w, d1);
        }
        const float dist = __fsub_rn(__fadd_rn(isq, cb_sq[c1]), __fmul_rn(2.f, d1));
        if (dist < bv || (dist == bv && c1 < bc)) { bv = dist; bc = c1; }
      }
    } else {
      // overflow fallback (P ~ 1e-9): exact full scan
      for (int c = q; c < KCB; c += 4) {
        const float4* e1 = (const float4*)(cb + c * DIM);
        float d1 = 0.f;
        #pragma unroll 4
        for (int qq = 0; qq < 64; ++qq) {
          const float4 a = e1[qq];
          d1 = fmaf(xb[(qq * 4 + 0) * 4096], a.x, d1);
          d1 = fmaf(xb[(qq * 4 + 1) * 4096], a.y, d1);
          d1 = fmaf(xb[(qq * 4 + 2) * 4096], a.z, d1);
          d1 = fmaf(xb[(qq * 4 + 3) * 4096], a.w, d1);
        }
        const float dist = __fsub_rn(__fadd_rn(isq, cb_sq[c]), __fmul_rn(2.f, d1));
        if (dist < bv || (dist == bv && c < bc)) { bv = dist; bc = c; }
      }
    }
    // combine 4 lanes (lexmin -> order independent)
    {
      float ov = __shfl_xor(bv, 1); int oc = __shfl_xor(bc, 1);
      if (ov < bv || (ov == bv && oc < bc)) { bv = ov; bc = oc; }
      ov = __shfl_xor(bv, 2); oc = __shfl_xor(bc, 2);
      if (ov < bv || (ov == bv && oc < bc)) { bv = ov; bc = oc; }
    }
    if (q == 0) { idxs[nl] = bc; atomicAdd(counts + bc, 1); }
  }
  __syncthreads();

  // ---- P3: one-hot encodings (coalesced, nontemporal) ----
  const int bh = blk;
  const int b  = bh >> 6, h = bh & 63;
  {
    float* base = enc + (size_t)bh * 65536 + t * 4;
    #pragma unroll 8
    for (int r = 0; r < 64; ++r) {
      const int bi = idxs[r];
      f4u v = {0.f, 0.f, 0.f, 0.f};
      if ((bi >> 2) == t) {
        if ((bi & 3) == 0) v.x = 1.f; else if ((bi & 3) == 1) v.y = 1.f;
        else if ((bi & 3) == 2) v.z = 1.f; else v.w = 1.f;
      }
      __builtin_nontemporal_store(v, (f4u*)(base + r * 1024));
    }
  }

  // ---- P4: xq straight-through + double loss partial ----
  const int w4 = (t & 15) * 4;
  const int cg = t >> 4;
  float qf[4][16];
  #pragma unroll
  for (int i = 0; i < 4; ++i) {
    const float4* rp = (const float4*)(cb + idxs[w4 + i] * DIM + cg * 16);
    #pragma unroll
    for (int jq = 0; jq < 4; ++jq) {
      const float4 v = rp[jq];
      qf[i][jq * 4 + 0] = v.x; qf[i][jq * 4 + 1] = v.y;
      qf[i][jq * 4 + 2] = v.z; qf[i][jq * 4 + 3] = v.w;
    }
  }

  double s = 0.0;
  #pragma unroll
  for (int j = 0; j < 16; ++j) {
    const int c = cg * 16 + j;
    const size_t off = ((size_t)b << 20) + ((size_t)c << 12) + (h << 6) + w4;
    const float4 xp = *(const float4*)(x + off);
    const float q0 = qf[0][j], q1 = qf[1][j], q2 = qf[2][j], q3 = qf[3][j];
    const float d0 = __fsub_rn(q0, xp.x), d1 = __fsub_rn(q1, xp.y);
    const float d2 = __fsub_rn(q2, xp.z), d3 = __fsub_rn(q3, xp.w);
    f4u o;
    o.x = __fadd_rn(xp.x, d0); o.y = __fadd_rn(xp.y, d1);
    o.z = __fadd_rn(xp.z, d2); o.w = __fadd_rn(xp.w, d3);
    __builtin_nontemporal_store(o, (f4u*)(out1 + off));
    s += (double)(d0*d0) + (double)(d1*d1) + (double)(d2*d2) + (double)(d3*d3);
  }
  #pragma unroll
  for (int off = 32; off > 0; off >>= 1) s += __shfl_down(s, off);
  if ((t & 63) == 0) sm[t >> 6] = s;
  __syncthreads();
  if (t == 0) partials[bh] = (sm[0] + sm[1]) + (sm[2] + sm[3]);
}

// ---------------------------------------------------------------------------
// k_final: loss + perplexity. grid 1 x 256
// ---------------------------------------------------------------------------
__global__ __launch_bounds__(256)
void k_final(const double* __restrict__ partials, const int* __restrict__ counts,
             float* __restrict__ out) {
  const int t = threadIdx.x;
  double s = 0.0;
  #pragma unroll
  for (int i = 0; i < 4; ++i) s += partials[t + i * 256];
  #pragma unroll
  for (int off = 32; off > 0; off >>= 1) s += __shfl_down(s, off);
  __shared__ double sm[4];
  __shared__ float smf[4];
  if ((t & 63) == 0) sm[t >> 6] = s;

  float ps = 0.f;
  #pragma unroll
  for (int i = 0; i < 4; ++i) {
    const float p = (float)counts[t + i * 256] * (1.0f / 65536.0f);
    ps += p * logf(1.0e10f + p);
  }
  #pragma unroll
  for (int off = 32; off > 0; off >>= 1) ps += __shfl_down(ps, off);
  if ((t & 63) == 0) smf[t >> 6] = ps;
  __syncthreads();
  if (t == 0) {
    const double tot = (sm[0] + sm[1]) + (sm[2] + sm[3]);
    const float mval = (float)(tot / 16777216.0);
    out[0] = mval + 0.25f * mval;
    out[PERP_OFF] = expf(-((smf[0] + smf[1]) + (smf[2] + smf[3])));
  }
}

// ---------------------------------------------------------------------------
extern "C" void kernel_launch(void* const* d_in, const int* in_sizes, int n_in,
                              void* d_out, int out_size, void* d_ws, size_t ws_size,
                              hipStream_t stream) {
  const float* x  = (const float*)d_in[0];   // (16,256,64,64) fp32
  const float* cb = (const float*)d_in[1];   // (1024,256) fp32
  float* out = (float*)d_out;
  char*  ws  = (char*)d_ws;

  int*            counts   = (int*)(ws + 0);                //   4 KB
  float*          cb_sq    = (float*)(ws + 4096);           //   4 KB
  double*         partials = (double*)(ws + 8192);          //   8 KB
  unsigned short* e_bf16   = (unsigned short*)(ws + 16384); // 512 KB

  k_prep <<<1024, 64, 0, stream>>>(cb, e_bf16, cb_sq, counts);
  k_mega <<<MEGA_BLOCKS, 256, 0, stream>>>(x, cb, e_bf16, cb_sq, out + 1,
                                           out + ENC_OFF, counts, partials);
  k_final<<<1, 256, 0, stream>>>(partials, counts, out);
}

// Round 9
// 523.871 us; speedup vs baseline: 1.3343x; 1.2233x over previous
//
#include <hip/hip_runtime.h>
#include <math.h>
#include <stdint.h>

typedef float f4u __attribute__((ext_vector_type(4), aligned(4)));
typedef unsigned int u4v __attribute__((ext_vector_type(4)));
typedef __attribute__((ext_vector_type(8))) short short8;   // 8 bf16 (4 VGPR)
typedef __attribute__((ext_vector_type(4))) float float4v;  // MFMA acc

#define DIM 256
#define KCB 1024
#define PERP_OFF 16777217
#define ENC_OFF  16777218
#define CAP 32
#define EPS 0.008f
#define NPB 128            // n per score block
#define SCORE_BLOCKS 512   // 512 * 128 = 65536 n

// ---------------------------------------------------------------------------
// numpy pairwise sum-of-squares of a 128-block (8 accumulators, pairwise
// combine); squares rounded separately; no fma contraction.
// ---------------------------------------------------------------------------
__device__ __forceinline__ float np_sumsq128(const float* a, int stride) {
  float r[8];
  #pragma unroll
  for (int j = 0; j < 8; ++j) { float v = a[j * stride]; r[j] = __fmul_rn(v, v); }
  #pragma unroll
  for (int i = 8; i < 128; i += 8) {
    #pragma unroll
    for (int j = 0; j < 8; ++j) {
      float v = a[(i + j) * stride];
      r[j] = __fadd_rn(r[j], __fmul_rn(v, v));
    }
  }
  float s01 = __fadd_rn(r[0], r[1]);
  float s23 = __fadd_rn(r[2], r[3]);
  float s45 = __fadd_rn(r[4], r[5]);
  float s67 = __fadd_rn(r[6], r[7]);
  return __fadd_rn(__fadd_rn(s01, s23), __fadd_rn(s45, s67));
}

__device__ __forceinline__ unsigned short f2bf(float f) {
  unsigned u = __float_as_uint(f);
  u += 0x7FFFu + ((u >> 16) & 1u);     // RNE
  return (unsigned short)(u >> 16);
}

// ---------------------------------------------------------------------------
// k_prep: e_bf16[k][d] (LINEAR layout), np-exact cb_sq[k], zero counts.
// grid 1024 x 64.
// ---------------------------------------------------------------------------
__global__ __launch_bounds__(64)
void k_prep(const float* __restrict__ cb, unsigned short* __restrict__ e_bf16,
            float* __restrict__ cb_sq, int* __restrict__ counts) {
  const int k = blockIdx.x;
  const int l = threadIdx.x;                  // 0..63
  float4 v = ((const float4*)(cb + k * DIM))[l];
  unsigned short bs[4] = {f2bf(v.x), f2bf(v.y), f2bf(v.z), f2bf(v.w)};
  *(ushort4*)(e_bf16 + k * DIM + l * 4) = *(ushort4*)bs;
  if (l == 0) {
    const float* p = cb + k * DIM;
    cb_sq[k] = __fadd_rn(np_sumsq128(p, 1), np_sumsq128(p + 128, 1));
    counts[k] = 0;
  }
}

// ---------------------------------------------------------------------------
// k_score v6: LDS-staged A-tiles. Per ct, the 16-code 8KB e_bf16 tile is
// staged once per BLOCK (reg-staged: global loads issued early, ds_write
// late) into a double-buffered, XOR-swizzled LDS tile shared by all 4 waves
// (4x less global traffic; ds_read_b128 ~12cy replaces ~200cy L2 hits).
// Swizzle: ushort col u (8-aligned granules) -> u ^ ((row&7)<<3), applied
// identically on write and read (bit-exact roundtrip; 16-way bank conflict
// -> 2-way = free). Capture: R8's windowed stale-threshold (cts 0..3 tight,
// then cross-lane reduce once per 4 cts; thr >= running min >= m_final ->
// captured set is a SUPERSET; end filter vs m_final+EPS recovers EXACTLY
// the two-pass set -> bitwise-identical downstream). 2 n-groups per wave
// (R6-proven ILP). grid 512 x 256.
// ---------------------------------------------------------------------------
__global__ __launch_bounds__(256, 3)
void k_score(const float* __restrict__ x, const unsigned short* __restrict__ e_bf16,
             const float* __restrict__ cb_sq, unsigned int* __restrict__ gcnt,
             unsigned short* __restrict__ glist) {
  __shared__ unsigned short As[2][16 * 256];    // 2 x 8KB, swizzled rows
  __shared__ unsigned int   lcnt[NPB];
  __shared__ unsigned short llist[NPB * CAP];   // 8KB
  __shared__ float          lsc[NPB * CAP];     // 16KB
  __shared__ float          lmin[NPB];

  const int t    = threadIdx.x;
  const int wv   = t >> 6;
  const int lane = t & 63;
  const int l15  = lane & 15;
  const int quad = lane >> 4;
  const int blk  = blockIdx.x;
  if (t < NPB) lcnt[t] = 0;

  // staging geometry: thread t copies 32B = 2 x 16B granules of the 8KB tile
  const int srow = t >> 4;                 // 0..15 (code row within tile)
  const int scol = (t & 15) * 16;          // ushort col, 16-aligned
  const int ssw  = (srow & 7) << 3;        // swizzle (ushort units)
  const int dst0 = srow * 256 + (scol ^ ssw);
  const int dst1 = srow * 256 + ((scol + 8) ^ ssw);

  // ---- B-frag setup: 2 n-groups x 8 K-steps, gathered from fp32 x ----
  short8 Bf[2][8];
  const int nbase = blk * NPB + wv * 32;
  #pragma unroll
  for (int g = 0; g < 2; ++g) {
    const int n = nbase + g * 16 + l15;
    const float* xb = x + (n >> 12) * 1048576 + (n & 4095);
    #pragma unroll
    for (int ks = 0; ks < 8; ++ks) {
      const int d0 = ks * 32 + quad * 8;
      union { unsigned short s[8]; short8 v; } u;
      #pragma unroll
      for (int j = 0; j < 8; ++j) u.s[j] = f2bf(xb[(d0 + j) * 4096]);
      Bf[g][ks] = u.v;
    }
  }

  // ---- stage tile 0 ----
  {
    const u4v* g0 = (const u4v*)(e_bf16 + t * 16);
    const u4v v0 = g0[0], v1 = g0[1];
    *(u4v*)(As[0] + dst0) = v0;
    *(u4v*)(As[0] + dst1) = v1;
  }
  __syncthreads();

  // ---- main loop: compute ct from LDS, stage ct+1 (issue-early/write-late)
  float mlane[2] = {1e30f, 1e30f};
  float thr[2]   = {1e30f, 1e30f};
  float mfin[2]  = {1e30f, 1e30f};
  for (int ct = 0; ct < 64; ++ct) {
    const int p = ct & 1;
    // issue next tile's global loads NOW (latency hides under compute)
    u4v n0, n1;
    const bool havenext = (ct < 63);
    if (havenext) {
      const u4v* gn = (const u4v*)(e_bf16 + (ct + 1) * 4096 + t * 16);
      n0 = gn[0]; n1 = gn[1];
    }
    // compute on As[p]
    float4v acc[2];
    acc[0] = (float4v){0.f, 0.f, 0.f, 0.f};
    acc[1] = (float4v){0.f, 0.f, 0.f, 0.f};
    const unsigned short* base = As[p] + l15 * 256;
    const int rsw = (l15 & 7) << 3;
    #pragma unroll
    for (int ks = 0; ks < 8; ++ks) {
      const int u = (quad * 8 + ks * 32) ^ rsw;
      const short8 a = *(const short8*)(base + u);
      acc[0] = __builtin_amdgcn_mfma_f32_16x16x32_bf16(a, Bf[0][ks], acc[0], 0, 0, 0);
      acc[1] = __builtin_amdgcn_mfma_f32_16x16x32_bf16(a, Bf[1][ks], acc[1], 0, 0, 0);
    }
    const float4 cs = *(const float4*)(cb_sq + ct * 16 + quad * 4);
    #pragma unroll
    for (int g = 0; g < 2; ++g) {
      float sa[4];
      sa[0] = fmaf(-2.f, acc[g].x, cs.x); sa[1] = fmaf(-2.f, acc[g].y, cs.y);
      sa[2] = fmaf(-2.f, acc[g].z, cs.z); sa[3] = fmaf(-2.f, acc[g].w, cs.w);
      const float cmin = fminf(fminf(sa[0], sa[1]), fminf(sa[2], sa[3]));
      mlane[g] = fminf(mlane[g], cmin);
      if (ct < 4) {                       // tight prologue: init thr exactly
        float bm = fminf(mlane[g], __shfl_xor(mlane[g], 16));
        bm = fminf(bm, __shfl_xor(bm, 32));
        mfin[g] = bm;
        thr[g]  = bm + EPS;
      }
      if (cmin <= thr[g]) {               // rare: skip whole capture block
        const int nl = wv * 32 + g * 16 + l15;
        #pragma unroll
        for (int r = 0; r < 4; ++r) {
          if (sa[r] <= thr[g]) {
            unsigned slot = atomicAdd(&lcnt[nl], 1u);
            if (slot < CAP) {
              llist[nl * CAP + slot] = (unsigned short)(ct * 16 + quad * 4 + r);
              lsc[nl * CAP + slot]   = sa[r];
            }
          }
        }
      }
    }
    if (ct >= 4 && (ct & 3) == 3) {       // window-end reduce (off crit path)
      #pragma unroll
      for (int g = 0; g < 2; ++g) {
        float bm = fminf(mlane[g], __shfl_xor(mlane[g], 16));
        bm = fminf(bm, __shfl_xor(bm, 32));
        mfin[g] = bm;
        thr[g]  = bm + EPS;
      }
    }
    // write next tile (write-late), then one barrier
    if (havenext) {
      *(u4v*)(As[p ^ 1] + dst0) = n0;
      *(u4v*)(As[p ^ 1] + dst1) = n1;
    }
    __syncthreads();
  }
  if (quad == 0) {
    #pragma unroll
    for (int g = 0; g < 2; ++g) lmin[wv * 32 + g * 16 + l15] = mfin[g];
  }
  __syncthreads();

  // ---- filter to EXACT two-pass set; compact in place; dump own row ----
  if (t < NPB) {
    const unsigned cnt = lcnt[t];
    unsigned outc = cnt;
    if (cnt <= CAP) {
      const float thrf = lmin[t] + EPS;
      unsigned j = 0;
      for (unsigned i = 0; i < cnt; ++i) {
        const unsigned short c = llist[t * CAP + i];
        if (lsc[t * CAP + i] <= thrf) llist[t * CAP + j++] = c;
      }
      outc = j;
    }
    gcnt[blk * NPB + t] = outc;

    u4v* gdst = (u4v*)(glist + (size_t)blk * NPB * CAP);
    const u4v* lsrc = (const u4v*)llist;
    #pragma unroll
    for (int j = 0; j < 4; ++j)
      __builtin_nontemporal_store(lsrc[t * 4 + j], gdst + t * 4 + j);
  }
}

// ---------------------------------------------------------------------------
// k_fused: insq + refine + epilogue, one block per (b,h) tile (64 n).
// Phase 1: 128 threads compute np-exact in_sq halves (2/n; __fadd_rn at
//   consume -> bit-identical, verified R6-R8).
// Phase 2: refine, 4 threads/n; per-candidate fmaf chains bit-identical;
//   lexmin over (dist,idx) is partition-free; 2x shfl_xor combine.
//   Overflow (cnt>CAP) -> exact full scan.
// Phase 3/4: enc one-hot (nontemporal) + xq straight-through + double loss.
// grid 1024 x 256.
// ---------------------------------------------------------------------------
__global__ __launch_bounds__(256)
void k_fused(const float* __restrict__ x, const float* __restrict__ cb,
             const float* __restrict__ cb_sq,
             const unsigned int* __restrict__ gcnt,
             const unsigned short* __restrict__ glist,
             float* __restrict__ out1, float* __restrict__ enc,
             int* __restrict__ counts, double* __restrict__ partials) {
  const int t  = threadIdx.x;
  const int bh = blockIdx.x;
  const int b  = bh >> 6, h = bh & 63;
  __shared__ float hpart[128];
  __shared__ int   idxs[64];

  // ---- phase 1: np-exact in_sq halves (threads 0..127) ----
  if (t < 128) {
    const int nl = t >> 1;
    const int p  = t & 1;
    const int n  = bh * 64 + nl;
    const float* xp = x + b * 1048576 + (n & 4095) + p * 128 * 4096;
    hpart[t] = np_sumsq128(xp, 4096);
  }
  __syncthreads();

  // ---- phase 2: refine, 4 threads per n ----
  {
    const int nl = t >> 2;            // 0..63
    const int q  = t & 3;
    const int n  = bh * 64 + nl;
    const unsigned cnt = gcnt[n];
    const float* xb = x + b * 1048576 + (n & 4095);
    const float isq = __fadd_rn(hpart[2 * nl], hpart[2 * nl + 1]);
    float bv = 1e30f; int bc = 0x7FFFFFFF;

    if (cnt <= CAP) {
      const unsigned short* lst = glist + (size_t)n * CAP;
      for (unsigned i = q; i < cnt; i += 4) {
        const int c1 = lst[i];
        const float4* e1 = (const float4*)(cb + c1 * DIM);
        float d1 = 0.f;
        #pragma unroll 4
        for (int qq = 0; qq < 64; ++qq) {
          const float4 a = e1[qq];
          d1 = fmaf(xb[(qq * 4 + 0) * 4096], a.x, d1);
          d1 = fmaf(xb[(qq * 4 + 1) * 4096], a.y, d1);
          d1 = fmaf(xb[(qq * 4 + 2) * 4096], a.z, d1);
          d1 = fmaf(xb[(qq * 4 + 3) * 4096], a.w, d1);
        }
        const float dist = __fsub_rn(__fadd_rn(isq, cb_sq[c1]), __fmul_rn(2.f, d1));
        if (dist < bv || (dist == bv && c1 < bc)) { bv = dist; bc = c1; }
      }
    } else {
      // overflow fallback (P ~ 1e-9): exact full scan
      for (int c = q; c < KCB; c += 4) {
        const float4* e1 = (const float4*)(cb + c * DIM);
        float d1 = 0.f;
        #pragma unroll 4
        for (int qq = 0; qq < 64; ++qq) {
          const float4 a = e1[qq];
          d1 = fmaf(xb[(qq * 4 + 0) * 4096], a.x, d1);
          d1 = fmaf(xb[(qq * 4 + 1) * 4096], a.y, d1);
          d1 = fmaf(xb[(qq * 4 + 2) * 4096], a.z, d1);
          d1 = fmaf(xb[(qq * 4 + 3) * 4096], a.w, d1);
        }
        const float dist = __fsub_rn(__fadd_rn(isq, cb_sq[c]), __fmul_rn(2.f, d1));
        if (dist < bv || (dist == bv && c < bc)) { bv = dist; bc = c; }
      }
    }
    // combine 4 lanes (lexmin -> order independent)
    {
      float ov = __shfl_xor(bv, 1); int oc = __shfl_xor(bc, 1);
      if (ov < bv || (ov == bv && oc < bc)) { bv = ov; bc = oc; }
      ov = __shfl_xor(bv, 2); oc = __shfl_xor(bc, 2);
      if (ov < bv || (ov == bv && oc < bc)) { bv = ov; bc = oc; }
    }
    if (q == 0) { idxs[nl] = bc; atomicAdd(counts + bc, 1); }
  }
  __syncthreads();

  // ---- phase 3: one-hot encodings (coalesced, nontemporal) ----
  {
    float* base = enc + (size_t)bh * 65536 + t * 4;
    #pragma unroll 8
    for (int r = 0; r < 64; ++r) {
      const int bi = idxs[r];
      f4u v = {0.f, 0.f, 0.f, 0.f};
      if ((bi >> 2) == t) {
        if ((bi & 3) == 0) v.x = 1.f; else if ((bi & 3) == 1) v.y = 1.f;
        else if ((bi & 3) == 2) v.z = 1.f; else v.w = 1.f;
      }
      __builtin_nontemporal_store(v, (f4u*)(base + r * 1024));
    }
  }

  // ---- phase 4: xq straight-through + double loss partial ----
  const int w4 = (t & 15) * 4;
  const int cg = t >> 4;
  float qf[4][16];
  #pragma unroll
  for (int i = 0; i < 4; ++i) {
    const float4* rp = (const float4*)(cb + idxs[w4 + i] * DIM + cg * 16);
    #pragma unroll
    for (int jq = 0; jq < 4; ++jq) {
      const float4 v = rp[jq];
      qf[i][jq * 4 + 0] = v.x; qf[i][jq * 4 + 1] = v.y;
      qf[i][jq * 4 + 2] = v.z; qf[i][jq * 4 + 3] = v.w;
    }
  }

  double s = 0.0;
  #pragma unroll
  for (int j = 0; j < 16; ++j) {
    const int c = cg * 16 + j;
    const size_t off = ((size_t)b << 20) + ((size_t)c << 12) + (h << 6) + w4;
    const float4 xp = *(const float4*)(x + off);
    const float q0 = qf[0][j], q1 = qf[1][j], q2 = qf[2][j], q3 = qf[3][j];
    const float d0 = __fsub_rn(q0, xp.x), d1 = __fsub_rn(q1, xp.y);
    const float d2 = __fsub_rn(q2, xp.z), d3 = __fsub_rn(q3, xp.w);
    f4u o;
    o.x = __fadd_rn(xp.x, d0); o.y = __fadd_rn(xp.y, d1);
    o.z = __fadd_rn(xp.z, d2); o.w = __fadd_rn(xp.w, d3);
    __builtin_nontemporal_store(o, (f4u*)(out1 + off));
    s += (double)(d0*d0) + (double)(d1*d1) + (double)(d2*d2) + (double)(d3*d3);
  }
  #pragma unroll
  for (int off = 32; off > 0; off >>= 1) s += __shfl_down(s, off);
  __shared__ double sm[4];
  if ((t & 63) == 0) sm[t >> 6] = s;
  __syncthreads();
  if (t == 0) partials[bh] = (sm[0] + sm[1]) + (sm[2] + sm[3]);
}

// ---------------------------------------------------------------------------
// k_final: loss + perplexity. grid 1 x 256
// ---------------------------------------------------------------------------
__global__ __launch_bounds__(256)
void k_final(const double* __restrict__ partials, const int* __restrict__ counts,
             float* __restrict__ out) {
  const int t = threadIdx.x;
  double s = 0.0;
  #pragma unroll
  for (int i = 0; i < 4; ++i) s += partials[t + i * 256];
  #pragma unroll
  for (int off = 32; off > 0; off >>= 1) s += __shfl_down(s, off);
  __shared__ double sm[4];
  __shared__ float smf[4];
  if ((t & 63) == 0) sm[t >> 6] = s;

  float ps = 0.f;
  #pragma unroll
  for (int i = 0; i < 4; ++i) {
    const float p = (float)counts[t + i * 256] * (1.0f / 65536.0f);
    ps += p * logf(1.0e10f + p);
  }
  #pragma unroll
  for (int off = 32; off > 0; off >>= 1) ps += __shfl_down(ps, off);
  if ((t & 63) == 0) smf[t >> 6] = ps;
  __syncthreads();
  if (t == 0) {
    const double tot = (sm[0] + sm[1]) + (sm[2] + sm[3]);
    const float mval = (float)(tot / 16777216.0);
    out[0] = mval + 0.25f * mval;
    out[PERP_OFF] = expf(-((smf[0] + smf[1]) + (smf[2] + smf[3])));
  }
}

// ---------------------------------------------------------------------------
extern "C" void kernel_launch(void* const* d_in, const int* in_sizes, int n_in,
                              void* d_out, int out_size, void* d_ws, size_t ws_size,
                              hipStream_t stream) {
  const float* x  = (const float*)d_in[0];   // (16,256,64,64) fp32
  const float* cb = (const float*)d_in[1];   // (1024,256) fp32
  float* out = (float*)d_out;
  char*  ws  = (char*)d_ws;

  int*            counts   = (int*)(ws + 0);                //   4 KB
  float*          cb_sq    = (float*)(ws + 4096);           //   4 KB
  double*         partials = (double*)(ws + 8192);          //   8 KB
  unsigned short* e_bf16   = (unsigned short*)(ws + 16384); // 512 KB
  unsigned int*   gcnt     = (unsigned int*)(ws + 540672);  // 256 KB
  unsigned short* glist    = (unsigned short*)(ws + 802816);// 4 MB

  k_prep <<<1024, 64, 0, stream>>>(cb, e_bf16, cb_sq, counts);
  k_score<<<SCORE_BLOCKS, 256, 0, stream>>>(x, e_bf16, cb_sq, gcnt, glist);
  k_fused<<<1024, 256, 0, stream>>>(x, cb, cb_sq, gcnt, glist, out + 1,
                                    out + ENC_OFF, counts, partials);
  k_final<<<1, 256, 0, stream>>>(partials, counts, out);
}